// Round 4
// baseline (204.010 us; speedup 1.0000x reference)
//
#include <hip/hip_runtime.h>

#define N_NODES 50000
#define N_EDGES 1600000
#define D_IN    256
#define HS      32

#define NB      625    // row buckets: 625*80 = 50000 exactly
#define ROWS_PB 80     // rows per bucket
#define CAP     3200   // slots per bucket (mean 2560, std ~51 -> +12.6 sigma)
#define EPB     4096   // edges per bin block (16 per thread)

#define MTILE   64     // proj rows per block
#define PROJ_B  ((N_NODES + MTILE - 1) / MTILE)   // 782
#define BIN_B   ((N_EDGES + EPB - 1) / EPB)       // 391

typedef __bf16 bf16x8 __attribute__((ext_vector_type(8)));
typedef float  floatx4 __attribute__((ext_vector_type(4)));

static __device__ __forceinline__ unsigned short f2bf(float f) {
    unsigned u = __float_as_uint(f);
    return (unsigned short)((u + 0x7FFFu + ((u >> 16) & 1u)) >> 16);  // RNE
}

// ---------------------------------------------------------------------------
// Pre-kernel: W -> bf16 B-fragments for mfma_f32_16x16x32_bf16.
// wfrag[(((s*6+t)*64+lane)*8)+j] = W[k=s*32+(lane>>4)*8+j][n=t*16+(lane&15)]
// of combined [256,96]. Block 0 also zeroes `fill` and sets rowptr[N].
// ---------------------------------------------------------------------------
__global__ __launch_bounds__(256) void wfrag_kernel(
    const float* __restrict__ Wq, const float* __restrict__ Wk,
    const float* __restrict__ Wv, unsigned short* __restrict__ wfrag,
    int* __restrict__ fill, int* __restrict__ rowptr)
{
    if (blockIdx.x == 0) {
        for (int b = threadIdx.x; b < NB; b += 256) fill[b] = 0;
        if (threadIdx.x == 0) rowptr[N_NODES] = N_EDGES;
    }
    const int i = blockIdx.x * blockDim.x + threadIdx.x;
    if (i >= 8 * 6 * 64 * 8) return;
    const int j    = i & 7;
    const int lane = (i >> 3) & 63;
    const int st   = i >> 9;
    const int t    = st % 6;
    const int s    = st / 6;
    const int k    = s * 32 + (lane >> 4) * 8 + j;
    const int col  = t * 16 + (lane & 15);
    float v;
    if      (col < 32) v = Wq[k * HS + col];
    else if (col < 64) v = Wk[k * HS + (col - 32)];
    else               v = Wv[k * HS + (col - 64)];
    wfrag[i] = f2bf(v);
}

// ---------------------------------------------------------------------------
// Projection (standalone so rocprof attributes time per phase). LDS-free:
// each lane's A-fragment for K-step s is 8 consecutive floats of ONE X row,
// zero intra-block reuse -> straight to registers, convert bf16 in-register,
// feed MFMA.
// ---------------------------------------------------------------------------
__global__ __launch_bounds__(256) void proj_kernel(
    const float* __restrict__ X, const unsigned short* __restrict__ wfrag,
    float* __restrict__ Q, unsigned int* __restrict__ KVp)
{
    const int t    = threadIdx.x;
    const int pb   = blockIdx.x;
    const int lane = t & 63;
    const int w    = t >> 6;
    const int quad = lane >> 4;
    const int m16  = lane & 15;
    const int row0 = pb * MTILE;

    const int arow = w * 16 + m16;
    const int grc  = min(row0 + arow, N_NODES - 1);   // clamp; never stored
    const float* xrow = X + (size_t)grc * D_IN;

    floatx4 acc[6];
#pragma unroll
    for (int nt = 0; nt < 6; nt++) acc[nt] = (floatx4)0.f;

#pragma unroll
    for (int s = 0; s < 8; s++) {
        const float4 a0 = *(const float4*)(xrow + s * 32 + quad * 8);
        const float4 a1 = *(const float4*)(xrow + s * 32 + quad * 8 + 4);
        union { bf16x8 v; unsigned short u[8]; } af;
        af.u[0] = f2bf(a0.x); af.u[1] = f2bf(a0.y);
        af.u[2] = f2bf(a0.z); af.u[3] = f2bf(a0.w);
        af.u[4] = f2bf(a1.x); af.u[5] = f2bf(a1.y);
        af.u[6] = f2bf(a1.z); af.u[7] = f2bf(a1.w);
        bf16x8 bfr[6];
#pragma unroll
        for (int nt = 0; nt < 6; nt++)
            bfr[nt] = *(const bf16x8*)(wfrag + (((s * 6 + nt) * 64 + lane) * 8));
#pragma unroll
        for (int nt = 0; nt < 6; nt++)
            acc[nt] = __builtin_amdgcn_mfma_f32_16x16x32_bf16(af.v, bfr[nt], acc[nt], 0, 0, 0);
    }

#pragma unroll
    for (int i = 0; i < 4; i++) {
        const int gr = row0 + w * 16 + quad * 4 + i;
        if (gr < N_NODES) {
#pragma unroll
            for (int nt = 0; nt < 2; nt++)
                Q[gr * HS + nt * 16 + m16] = acc[nt][i];
#pragma unroll
            for (int p = 0; p < 2; p++) {
                const int j = p * 16 + m16;
                const unsigned kb = f2bf(acc[2 + p][i]);
                const unsigned vb = f2bf(acc[4 + p][i]);
                KVp[gr * HS + j] = (kb << 16) | vb;
            }
        }
    }
}

// ---------------------------------------------------------------------------
// Edge binning (standalone). r2 occupancy math showed these 391 blocks ARE
// the fused kernel's 44 us critical path. Suspected mechanism: pairs slots
// interleave different blocks' writes within 64B lines -> cross-XCD L2
// ownership churn. Fix attempt: NONTEMPORAL stores for the pairs scatter
// (no-allocate, stream to memory); NB=625 halves global fill atomics.
// ---------------------------------------------------------------------------
__global__ __launch_bounds__(256) void bin_kernel(
    const int* __restrict__ er, const int* __restrict__ ec,
    int* __restrict__ fill, unsigned int* __restrict__ pairs)
{
    __shared__ int lcnt[NB];   // 2.5 KB

    const int t  = threadIdx.x;
    const int e0 = blockIdx.x * EPB;
    const int e1 = min(e0 + EPB, N_EDGES);

    for (int b = t; b < NB; b += 256) lcnt[b] = 0;
    __syncthreads();

    int rl[16], cl[16];
#pragma unroll
    for (int i = 0; i < 16; i++) {
        const int e = e0 + t + i * 256;
        if (e < e1) {
            rl[i] = er[e];
            cl[i] = ec[e];
            atomicAdd(&lcnt[rl[i] / ROWS_PB], 1);
        }
    }
    __syncthreads();

    for (int b = t; b < NB; b += 256) {
        const int c = lcnt[b];
        lcnt[b] = (c > 0) ? atomicAdd(&fill[b], c) : 0;  // base slot (contiguous chunk)
    }
    __syncthreads();

#pragma unroll
    for (int i = 0; i < 16; i++) {
        const int e = e0 + t + i * 256;
        if (e < e1) {
            const int r = rl[i];
            const int b = r / ROWS_PB;
            const int slot = atomicAdd(&lcnt[b], 1);
            __builtin_nontemporal_store(
                ((unsigned)(r - b * ROWS_PB) << 16) | (unsigned)cl[i],
                &pairs[(size_t)b * CAP + slot]);
        }
    }
}

// ---------------------------------------------------------------------------
// Phase B: one block per bucket. Computes its own base offset (reduction of
// fill[0..b-1], L2-broadcast), then PER-WAVE LDS row-histograms (4 copies ->
// low same-address atomic contention), scan converts the copies into
// per-wave scatter bases; emits rowptr; coalesced copy-out.
// r4 FIX: hist zero-init is a strided loop — 4*ROWS_PB=320 > 256 threads,
// the r3 `if (t < 320)` guard left hist[3][16..79] garbage -> OOB scatter
// -> crash. (Parameter change invalidated a hidden one-thread-per-entry
// assumption.)
// ---------------------------------------------------------------------------
__global__ __launch_bounds__(256) void place_kernel(
    const unsigned int* __restrict__ pairs, const int* __restrict__ fill,
    int* __restrict__ rowptr, int* __restrict__ col_sorted)
{
    __shared__ int hist[4][ROWS_PB];   // per-wave histograms -> scatter bases
    __shared__ int s[128];             // inclusive-scan buffer (ROWS_PB <= 128)
    __shared__ int red[256];
    __shared__ int stage[CAP];

    const int b = blockIdx.x;
    const int t = threadIdx.x;
    const int w = t >> 6;
    const int n = fill[b];
    const unsigned int* pb = pairs + (size_t)b * CAP;

    // base = sum of fill[0..b-1]
    int partial = 0;
    for (int i = t; i < b; i += 256) partial += fill[i];
    red[t] = partial;
    for (int i = t; i < 4 * ROWS_PB; i += 256) ((int*)hist)[i] = 0;
    __syncthreads();
#pragma unroll
    for (int ofs = 128; ofs > 0; ofs >>= 1) {
        if (t < ofs) red[t] += red[t + ofs];
        __syncthreads();
    }
    const int base = red[0];

    unsigned pl[(CAP + 255) / 256];
#pragma unroll
    for (int k = 0; k < (CAP + 255) / 256; k++) {
        const int i = t + k * 256;
        if (i < n) {
            pl[k] = pb[i];
            atomicAdd(&hist[w][pl[k] >> 16], 1);   // own wave's copy
        }
    }
    __syncthreads();

    // inclusive scan of per-row totals
    if (t < 128)
        s[t] = (t < ROWS_PB) ? (hist[0][t] + hist[1][t] + hist[2][t] + hist[3][t]) : 0;
    __syncthreads();
#pragma unroll
    for (int ofs = 1; ofs < 128; ofs <<= 1) {
        int u = 0;
        if (t < 128 && t >= ofs) u = s[t - ofs];
        __syncthreads();
        if (t < 128) s[t] += u;
        __syncthreads();
    }
    if (t < ROWS_PB) {
        const int h0 = hist[0][t], h1 = hist[1][t], h2 = hist[2][t], h3 = hist[3][t];
        const int excl = s[t] - (h0 + h1 + h2 + h3);
        rowptr[b * ROWS_PB + t] = base + excl;
        // per-wave exclusive bases within this row's slice
        int run = excl;
        hist[0][t] = run; run += h0;
        hist[1][t] = run; run += h1;
        hist[2][t] = run; run += h2;
        hist[3][t] = run;
    }
    __syncthreads();

#pragma unroll
    for (int k = 0; k < (CAP + 255) / 256; k++) {
        const int i = t + k * 256;
        if (i < n) {
            const unsigned p = pl[k];
            const int pos = atomicAdd(&hist[w][p >> 16], 1);  // own wave's counter
            stage[pos] = (int)(p & 0xFFFFu);
        }
    }
    __syncthreads();

    for (int i = t; i < n; i += 256)
        col_sorted[base + i] = stage[i];
}

// ---------------------------------------------------------------------------
// Aggregation: one wave per row; lane = slot*8+comp. 32 edges per iteration
// as 4 guarded batches of 8 (wave-uniform guards): col loads, then KV
// gathers, then compute. K = hi16, V = lo16. No atomics.
// ---------------------------------------------------------------------------
__global__ __launch_bounds__(256) void aggregate_kernel(
    const int* __restrict__ rowptr, const int* __restrict__ col,
    const float* __restrict__ Q, const unsigned int* __restrict__ KVp,
    float* __restrict__ out)
{
    const int lane = threadIdx.x & 63;
    const int r    = (blockIdx.x * blockDim.x + threadIdx.x) >> 6;
    if (r >= N_NODES) return;
    const int comp = lane & 7;
    const int slot = lane >> 3;

    const float4 q4 = *(const float4*)(Q + r * HS + comp * 4);
    const int start = rowptr[r];
    const int end   = rowptr[r + 1];
    const int last  = end - 1;
    const float scale = 0.17677669529663687f;  // 1/sqrt(32)

    float accD = 0.f;
    float n0 = 0.f, n1 = 0.f, n2 = 0.f, n3 = 0.f;

    for (int e0 = start; e0 < end; e0 += 32) {
        int   cc[4];
        uint4 kv[4];
#pragma unroll
        for (int b = 0; b < 4; b++)
            if (e0 + 8 * b < end)
                cc[b] = col[min(e0 + 8 * b + slot, last)];
#pragma unroll
        for (int b = 0; b < 4; b++)
            if (e0 + 8 * b < end)
                kv[b] = *(const uint4*)(KVp + (size_t)cc[b] * HS + comp * 4);
#pragma unroll
        for (int b = 0; b < 4; b++) {
            if (e0 + 8 * b < end) {
                float p = q4.x * __uint_as_float(kv[b].x & 0xFFFF0000u)
                        + q4.y * __uint_as_float(kv[b].y & 0xFFFF0000u)
                        + q4.z * __uint_as_float(kv[b].z & 0xFFFF0000u)
                        + q4.w * __uint_as_float(kv[b].w & 0xFFFF0000u);
#pragma unroll
                for (int ofs = 1; ofs < 8; ofs <<= 1)
                    p += __shfl_xor(p, ofs, 64);
                const float ex = (e0 + 8 * b + slot < end) ? __expf(p * scale) : 0.f;
                accD += ex;
                n0 += ex * __uint_as_float(kv[b].x << 16);
                n1 += ex * __uint_as_float(kv[b].y << 16);
                n2 += ex * __uint_as_float(kv[b].z << 16);
                n3 += ex * __uint_as_float(kv[b].w << 16);
            }
        }
    }

    // reduce over the 8 slots
#pragma unroll
    for (int ofs = 8; ofs < 64; ofs <<= 1) {
        accD += __shfl_xor(accD, ofs, 64);
        n0 += __shfl_xor(n0, ofs, 64);
        n1 += __shfl_xor(n1, ofs, 64);
        n2 += __shfl_xor(n2, ofs, 64);
        n3 += __shfl_xor(n3, ofs, 64);
    }

    if (slot == 0) {
        const float inv = (accD > 0.f) ? 1.f / accD : 0.f;
        float4 o;
        o.x = n0 * inv; o.y = n1 * inv; o.z = n2 * inv; o.w = n3 * inv;
        *(float4*)(out + r * HS + comp * 4) = o;
    }
}

extern "C" void kernel_launch(void* const* d_in, const int* in_sizes, int n_in,
                              void* d_out, int out_size, void* d_ws, size_t ws_size,
                              hipStream_t stream)
{
    const float* X  = (const float*)d_in[0];
    const float* Wq = (const float*)d_in[1];
    const float* Wk = (const float*)d_in[2];
    const float* Wv = (const float*)d_in[3];
    const int*   ei = (const int*)d_in[4];
    const int* er = ei;
    const int* ec = ei + N_EDGES;

    float* out = (float*)d_out;

    // workspace: Q | KVp | fill | rowptr | wfrag | pairs | col_sorted
    float* Q          = (float*)d_ws;
    unsigned int* KVp = (unsigned int*)(Q + (size_t)N_NODES * HS);
    int* fill         = (int*)(KVp + (size_t)N_NODES * HS);
    int* rowptr       = fill + NB;
    unsigned short* wfrag = (unsigned short*)(rowptr + (N_NODES + 1));
    unsigned int* pairs   = (unsigned int*)(wfrag + 8 * 6 * 64 * 8);
    int* col_sorted   = (int*)(pairs + (size_t)NB * CAP);

    wfrag_kernel<<<(8 * 6 * 64 * 8 + 255) / 256, 256, 0, stream>>>(
        Wq, Wk, Wv, wfrag, fill, rowptr);

    bin_kernel<<<BIN_B, 256, 0, stream>>>(er, ec, fill, pairs);

    proj_kernel<<<PROJ_B, 256, 0, stream>>>(X, wfrag, Q, KVp);

    place_kernel<<<NB, 256, 0, stream>>>(pairs, fill, rowptr, col_sorted);

    aggregate_kernel<<<(N_NODES * 64 + 255) / 256, 256, 0, stream>>>(
        rowptr, col_sorted, Q, KVp, out);
}

// Round 5
// 168.001 us; speedup vs baseline: 1.2143x; 1.2143x over previous
//
#include <hip/hip_runtime.h>

#define N_NODES 50000
#define N_EDGES 1600000
#define D_IN    256
#define HS      32

#define NB      625    // row buckets: 625*80 = 50000 exactly
#define ROWS_PB 80     // rows per bucket
#define CAP     3200   // slots per bucket (mean 2560, std ~51 -> +12.6 sigma)
#define EPB     8192   // edges per bin block (32 per thread)
#define BIN_B   ((N_EDGES + EPB - 1) / EPB)       // 196

#define MTILE   64     // proj rows per block
#define PROJ_B  ((N_NODES + MTILE - 1) / MTILE)   // 782

// fused grid: mod-5 interleave, m==4 -> bin (196), m<4 -> proj (784 slots, 782 used)
#define GRID_F  (5 * BIN_B)                       // 980

typedef __bf16 bf16x8 __attribute__((ext_vector_type(8)));
typedef float  floatx4 __attribute__((ext_vector_type(4)));

static __device__ __forceinline__ unsigned short f2bf(float f) {
    unsigned u = __float_as_uint(f);
    return (unsigned short)((u + 0x7FFFu + ((u >> 16) & 1u)) >> 16);  // RNE
}

// ---------------------------------------------------------------------------
// Pre-kernel: W -> bf16 B-fragments for mfma_f32_16x16x32_bf16.
// wfrag[(((s*6+t)*64+lane)*8)+j] = W[k=s*32+(lane>>4)*8+j][n=t*16+(lane&15)]
// of combined [256,96]. Must be its own dispatch: proj reads wfrag, so they
// can't share a kernel. fill is zeroed by hipMemsetAsync now.
// ---------------------------------------------------------------------------
__global__ __launch_bounds__(256) void wfrag_kernel(
    const float* __restrict__ Wq, const float* __restrict__ Wk,
    const float* __restrict__ Wv, unsigned short* __restrict__ wfrag,
    int* __restrict__ rowptr)
{
    const int i = blockIdx.x * blockDim.x + threadIdx.x;
    if (i == 0) rowptr[N_NODES] = N_EDGES;
    if (i >= 8 * 6 * 64 * 8) return;
    const int j    = i & 7;
    const int lane = (i >> 3) & 63;
    const int st   = i >> 9;
    const int t    = st % 6;
    const int s    = st / 6;
    const int k    = s * 32 + (lane >> 4) * 8 + j;
    const int col  = t * 16 + (lane & 15);
    float v;
    if      (col < 32) v = Wq[k * HS + col];
    else if (col < 64) v = Wk[k * HS + (col - 32)];
    else               v = Wv[k * HS + (col - 64)];
    wfrag[i] = f2bf(v);
}

// ---------------------------------------------------------------------------
// Fused proj + bin (r5). r2 measured that proj hides in bin's shadow when
// co-dispatched (m114 co-scheduling); r4's split removed that overlap and
// cost ~45 us. Re-fused with the bin branch REBUILT:
//
// bin (r4 counters: 75 MB WRITE_SIZE for 6.4 MB payload = 12x partial-line
// amplification from the random 4B scatter; nontemporal made it worse by
// bypassing L2 merge): now LDS-staged bucket sort. Per block: histogram of
// 8192 edges over 625 buckets, exclusive scan, scatter into LDS stage
// (sorted by bucket), then write each bucket's chunk CONTIGUOUSLY to its
// globally-reserved slice (base via one fill atomicAdd per bucket). Writes
// become runs of ~13 dwords -> L2 merges -> ~2x payload instead of 12x.
// pairs payload is now (r<<16)|c with the GLOBAL row (50000 < 2^16).
// ---------------------------------------------------------------------------
__global__ __launch_bounds__(256) void proj_bin_kernel(
    const float* __restrict__ X, const unsigned short* __restrict__ wfrag,
    float* __restrict__ Q, unsigned int* __restrict__ KVp,
    const int* __restrict__ er, const int* __restrict__ ec,
    int* __restrict__ fill, unsigned int* __restrict__ pairs)
{
    // bin-branch LDS: lcnt|excl|gbase [NB each] + sscan[256] + stage[EPB]
    __shared__ __align__(16) int lds[3 * NB + 256 + EPB];   // 41.3 KB

    const int t = threadIdx.x;
    const int m = blockIdx.x % 5;

    if (m != 4) {
        // ---------------- projection (LDS-free, r2-verified) ----------------
        const int pb = (blockIdx.x / 5) * 4 + m;
        if (pb >= PROJ_B) return;
        const int lane = t & 63;
        const int w    = t >> 6;
        const int quad = lane >> 4;
        const int m16  = lane & 15;
        const int row0 = pb * MTILE;

        const int arow = w * 16 + m16;
        const int grc  = min(row0 + arow, N_NODES - 1);   // clamp; never stored
        const float* xrow = X + (size_t)grc * D_IN;

        floatx4 acc[6];
#pragma unroll
        for (int nt = 0; nt < 6; nt++) acc[nt] = (floatx4)0.f;

#pragma unroll
        for (int s = 0; s < 8; s++) {
            const float4 a0 = *(const float4*)(xrow + s * 32 + quad * 8);
            const float4 a1 = *(const float4*)(xrow + s * 32 + quad * 8 + 4);
            union { bf16x8 v; unsigned short u[8]; } af;
            af.u[0] = f2bf(a0.x); af.u[1] = f2bf(a0.y);
            af.u[2] = f2bf(a0.z); af.u[3] = f2bf(a0.w);
            af.u[4] = f2bf(a1.x); af.u[5] = f2bf(a1.y);
            af.u[6] = f2bf(a1.z); af.u[7] = f2bf(a1.w);
            bf16x8 bfr[6];
#pragma unroll
            for (int nt = 0; nt < 6; nt++)
                bfr[nt] = *(const bf16x8*)(wfrag + (((s * 6 + nt) * 64 + lane) * 8));
#pragma unroll
            for (int nt = 0; nt < 6; nt++)
                acc[nt] = __builtin_amdgcn_mfma_f32_16x16x32_bf16(af.v, bfr[nt], acc[nt], 0, 0, 0);
        }

#pragma unroll
        for (int i = 0; i < 4; i++) {
            const int gr = row0 + w * 16 + quad * 4 + i;
            if (gr < N_NODES) {
#pragma unroll
                for (int nt = 0; nt < 2; nt++)
                    Q[gr * HS + nt * 16 + m16] = acc[nt][i];
#pragma unroll
                for (int p = 0; p < 2; p++) {
                    const int j = p * 16 + m16;
                    const unsigned kb = f2bf(acc[2 + p][i]);
                    const unsigned vb = f2bf(acc[4 + p][i]);
                    KVp[gr * HS + j] = (kb << 16) | vb;
                }
            }
        }
    } else {
        // ---------------- edge binning (LDS-staged sort) ----------------
        int* lcnt       = lds;               // hist, later cursor
        int* excl       = lds + NB;          // per-bucket stage offset
        int* gbase      = lds + 2 * NB;      // per-bucket global chunk base
        int* sscan      = lds + 3 * NB;      // 256-entry scan buffer
        unsigned* stage = (unsigned*)(lds + 3 * NB + 256);

        const int bb   = blockIdx.x / 5;
        const int e0   = bb * EPB;
        const int e1   = min(e0 + EPB, N_EDGES);
        const int nloc = e1 - e0;

        for (int i = t; i < NB; i += 256) lcnt[i] = 0;
        __syncthreads();

        // pass 1: bucket histogram
#pragma unroll
        for (int i = 0; i < EPB / 256; i++) {
            const int e = e0 + t + i * 256;
            if (e < e1) atomicAdd(&lcnt[er[e] / ROWS_PB], 1);
        }
        __syncthreads();

        // reserve global chunks + exclusive scan of lcnt -> excl
        for (int i = t; i < NB; i += 256) gbase[i] = atomicAdd(&fill[i], lcnt[i]);
        int a0 = 0;
#pragma unroll
        for (int j = 0; j < 3; j++) {
            const int idx = t * 3 + j;
            if (idx < NB) a0 += lcnt[idx];
        }
        sscan[t] = a0;
        __syncthreads();
#pragma unroll
        for (int ofs = 1; ofs < 256; ofs <<= 1) {
            const int u = (t >= ofs) ? sscan[t - ofs] : 0;
            __syncthreads();
            sscan[t] += u;
            __syncthreads();
        }
        int run = sscan[t] - a0;   // exclusive prefix of this thread's range
#pragma unroll
        for (int j = 0; j < 3; j++) {
            const int idx = t * 3 + j;
            if (idx < NB) { excl[idx] = run; run += lcnt[idx]; }
        }
        __syncthreads();

        // cursor = excl; scatter edges into LDS stage sorted by bucket
        for (int i = t; i < NB; i += 256) lcnt[i] = excl[i];
        __syncthreads();
#pragma unroll
        for (int i = 0; i < EPB / 256; i++) {
            const int e = e0 + t + i * 256;
            if (e < e1) {
                const int r = er[e];
                const unsigned v = ((unsigned)r << 16) | (unsigned)ec[e];
                const int pos = atomicAdd(&lcnt[r / ROWS_PB], 1);
                stage[pos] = v;
            }
        }
        __syncthreads();

        // coalesced chunk write-out: consecutive i -> consecutive dst in chunk
        for (int i = t; i < nloc; i += 256) {
            const unsigned v = stage[i];
            const int bk = (int)(v >> 16) / ROWS_PB;
            pairs[(size_t)bk * CAP + gbase[bk] + (i - excl[bk])] = v;
        }
    }
}

// ---------------------------------------------------------------------------
// Phase B: one block per bucket. base offset via fill-prefix reduction;
// per-wave LDS row-histograms; scan -> per-wave scatter bases; rowptr;
// coalesced copy-out. r5: pairs payload carries GLOBAL row -> local row is
// (p>>16) - b*ROWS_PB. hist zero-init stays the r4 strided loop (320 > 256).
// ---------------------------------------------------------------------------
__global__ __launch_bounds__(256) void place_kernel(
    const unsigned int* __restrict__ pairs, const int* __restrict__ fill,
    int* __restrict__ rowptr, int* __restrict__ col_sorted)
{
    __shared__ int hist[4][ROWS_PB];
    __shared__ int s[128];
    __shared__ int red[256];
    __shared__ int stage[CAP];

    const int b = blockIdx.x;
    const int t = threadIdx.x;
    const int w = t >> 6;
    const int n = fill[b];
    const int rbase = b * ROWS_PB;
    const unsigned int* pb = pairs + (size_t)b * CAP;

    // base = sum of fill[0..b-1]
    int partial = 0;
    for (int i = t; i < b; i += 256) partial += fill[i];
    red[t] = partial;
    for (int i = t; i < 4 * ROWS_PB; i += 256) ((int*)hist)[i] = 0;
    __syncthreads();
#pragma unroll
    for (int ofs = 128; ofs > 0; ofs >>= 1) {
        if (t < ofs) red[t] += red[t + ofs];
        __syncthreads();
    }
    const int base = red[0];

    unsigned pl[(CAP + 255) / 256];
#pragma unroll
    for (int k = 0; k < (CAP + 255) / 256; k++) {
        const int i = t + k * 256;
        if (i < n) {
            pl[k] = pb[i];
            atomicAdd(&hist[w][(int)(pl[k] >> 16) - rbase], 1);
        }
    }
    __syncthreads();

    if (t < 128)
        s[t] = (t < ROWS_PB) ? (hist[0][t] + hist[1][t] + hist[2][t] + hist[3][t]) : 0;
    __syncthreads();
#pragma unroll
    for (int ofs = 1; ofs < 128; ofs <<= 1) {
        int u = 0;
        if (t < 128 && t >= ofs) u = s[t - ofs];
        __syncthreads();
        if (t < 128) s[t] += u;
        __syncthreads();
    }
    if (t < ROWS_PB) {
        const int h0 = hist[0][t], h1 = hist[1][t], h2 = hist[2][t], h3 = hist[3][t];
        const int excl = s[t] - (h0 + h1 + h2 + h3);
        rowptr[rbase + t] = base + excl;
        int run = excl;
        hist[0][t] = run; run += h0;
        hist[1][t] = run; run += h1;
        hist[2][t] = run; run += h2;
        hist[3][t] = run;
    }
    __syncthreads();

#pragma unroll
    for (int k = 0; k < (CAP + 255) / 256; k++) {
        const int i = t + k * 256;
        if (i < n) {
            const unsigned p = pl[k];
            const int pos = atomicAdd(&hist[w][(int)(p >> 16) - rbase], 1);
            stage[pos] = (int)(p & 0xFFFFu);
        }
    }
    __syncthreads();

    for (int i = t; i < n; i += 256)
        col_sorted[base + i] = stage[i];
}

// ---------------------------------------------------------------------------
// Aggregation: one wave per row; lane = slot*8+comp. 32 edges per iteration
// as 4 guarded batches of 8 (wave-uniform guards). K = hi16, V = lo16.
// ---------------------------------------------------------------------------
__global__ __launch_bounds__(256) void aggregate_kernel(
    const int* __restrict__ rowptr, const int* __restrict__ col,
    const float* __restrict__ Q, const unsigned int* __restrict__ KVp,
    float* __restrict__ out)
{
    const int lane = threadIdx.x & 63;
    const int r    = (blockIdx.x * blockDim.x + threadIdx.x) >> 6;
    if (r >= N_NODES) return;
    const int comp = lane & 7;
    const int slot = lane >> 3;

    const float4 q4 = *(const float4*)(Q + r * HS + comp * 4);
    const int start = rowptr[r];
    const int end   = rowptr[r + 1];
    const int last  = end - 1;
    const float scale = 0.17677669529663687f;  // 1/sqrt(32)

    float accD = 0.f;
    float n0 = 0.f, n1 = 0.f, n2 = 0.f, n3 = 0.f;

    for (int e0 = start; e0 < end; e0 += 32) {
        int   cc[4];
        uint4 kv[4];
#pragma unroll
        for (int b = 0; b < 4; b++)
            if (e0 + 8 * b < end)
                cc[b] = col[min(e0 + 8 * b + slot, last)];
#pragma unroll
        for (int b = 0; b < 4; b++)
            if (e0 + 8 * b < end)
                kv[b] = *(const uint4*)(KVp + (size_t)cc[b] * HS + comp * 4);
#pragma unroll
        for (int b = 0; b < 4; b++) {
            if (e0 + 8 * b < end) {
                float p = q4.x * __uint_as_float(kv[b].x & 0xFFFF0000u)
                        + q4.y * __uint_as_float(kv[b].y & 0xFFFF0000u)
                        + q4.z * __uint_as_float(kv[b].z & 0xFFFF0000u)
                        + q4.w * __uint_as_float(kv[b].w & 0xFFFF0000u);
#pragma unroll
                for (int ofs = 1; ofs < 8; ofs <<= 1)
                    p += __shfl_xor(p, ofs, 64);
                const float ex = (e0 + 8 * b + slot < end) ? __expf(p * scale) : 0.f;
                accD += ex;
                n0 += ex * __uint_as_float(kv[b].x << 16);
                n1 += ex * __uint_as_float(kv[b].y << 16);
                n2 += ex * __uint_as_float(kv[b].z << 16);
                n3 += ex * __uint_as_float(kv[b].w << 16);
            }
        }
    }

#pragma unroll
    for (int ofs = 8; ofs < 64; ofs <<= 1) {
        accD += __shfl_xor(accD, ofs, 64);
        n0 += __shfl_xor(n0, ofs, 64);
        n1 += __shfl_xor(n1, ofs, 64);
        n2 += __shfl_xor(n2, ofs, 64);
        n3 += __shfl_xor(n3, ofs, 64);
    }

    if (slot == 0) {
        const float inv = (accD > 0.f) ? 1.f / accD : 0.f;
        float4 o;
        o.x = n0 * inv; o.y = n1 * inv; o.z = n2 * inv; o.w = n3 * inv;
        *(float4*)(out + r * HS + comp * 4) = o;
    }
}

extern "C" void kernel_launch(void* const* d_in, const int* in_sizes, int n_in,
                              void* d_out, int out_size, void* d_ws, size_t ws_size,
                              hipStream_t stream)
{
    const float* X  = (const float*)d_in[0];
    const float* Wq = (const float*)d_in[1];
    const float* Wk = (const float*)d_in[2];
    const float* Wv = (const float*)d_in[3];
    const int*   ei = (const int*)d_in[4];
    const int* er = ei;
    const int* ec = ei + N_EDGES;

    float* out = (float*)d_out;

    // workspace: Q | KVp | fill | rowptr | wfrag | pairs | col_sorted
    float* Q          = (float*)d_ws;
    unsigned int* KVp = (unsigned int*)(Q + (size_t)N_NODES * HS);
    int* fill         = (int*)(KVp + (size_t)N_NODES * HS);
    int* rowptr       = fill + NB;
    unsigned short* wfrag = (unsigned short*)(rowptr + (N_NODES + 1));
    unsigned int* pairs   = (unsigned int*)(wfrag + 8 * 6 * 64 * 8);
    int* col_sorted   = (int*)(pairs + (size_t)NB * CAP);

    hipMemsetAsync(fill, 0, NB * sizeof(int), stream);

    wfrag_kernel<<<(8 * 6 * 64 * 8 + 255) / 256, 256, 0, stream>>>(
        Wq, Wk, Wv, wfrag, rowptr);

    proj_bin_kernel<<<GRID_F, 256, 0, stream>>>(
        X, wfrag, Q, KVp, er, ec, fill, pairs);

    place_kernel<<<NB, 256, 0, stream>>>(pairs, fill, rowptr, col_sorted);

    aggregate_kernel<<<(N_NODES * 64 + 255) / 256, 256, 0, stream>>>(
        rowptr, col_sorted, Q, KVp, out);
}

// Round 6
// 160.342 us; speedup vs baseline: 1.2723x; 1.0478x over previous
//
#include <hip/hip_runtime.h>

#define N_NODES 50000
#define N_EDGES 1600000
#define D_IN    256
#define HS      32

#define NB      1250   // row buckets: 1250*40 = 50000 exactly (r2-measured-best)
#define ROWS_PB 40     // rows per bucket
#define CAP     1600   // slots per bucket (mean 1280, std ~36 -> +8.9 sigma; passed r1/r2)
#define EPB     4096   // edges per bin block (16 per thread)
#define BIN_B   ((N_EDGES + EPB - 1) / EPB)       // 391

#define MTILE   64     // proj rows per block
#define PROJ_B  ((N_NODES + MTILE - 1) / MTILE)   // 782
#define GRID_F  (PROJ_B + BIN_B)                  // 1173, mod-3 interleave

typedef __bf16 bf16x8 __attribute__((ext_vector_type(8)));
typedef float  floatx4 __attribute__((ext_vector_type(4)));

static __device__ __forceinline__ unsigned short f2bf(float f) {
    unsigned u = __float_as_uint(f);
    return (unsigned short)((u + 0x7FFFu + ((u >> 16) & 1u)) >> 16);  // RNE
}

// ---------------------------------------------------------------------------
// Pre-kernel: W -> bf16 B-fragments for mfma_f32_16x16x32_bf16.
// wfrag[(((s*6+t)*64+lane)*8)+j] = W[k=s*32+(lane>>4)*8+j][n=t*16+(lane&15)]
// of combined [256,96].
// ---------------------------------------------------------------------------
__global__ __launch_bounds__(256) void wfrag_kernel(
    const float* __restrict__ Wq, const float* __restrict__ Wk,
    const float* __restrict__ Wv, unsigned short* __restrict__ wfrag)
{
    const int i = blockIdx.x * blockDim.x + threadIdx.x;
    if (i >= 8 * 6 * 64 * 8) return;
    const int j    = i & 7;
    const int lane = (i >> 3) & 63;
    const int st   = i >> 9;
    const int t    = st % 6;
    const int s    = st / 6;
    const int k    = s * 32 + (lane >> 4) * 8 + j;
    const int col  = t * 16 + (lane & 15);
    float v;
    if      (col < 32) v = Wq[k * HS + col];
    else if (col < 64) v = Wk[k * HS + (col - 32)];
    else               v = Wv[k * HS + (col - 64)];
    wfrag[i] = f2bf(v);
}

// ---------------------------------------------------------------------------
// Fused proj + bin, mod-3 grid (r6 = r2-measured-best bin + r5 LDS-free proj).
// Evidence trail: r2 fused bin (this exact recipe) = 44 us; r4 nontemporal
// scatter = 60; r5 LDS-sorted chunks = 57 (fixed WRITE_SIZE 75->22 MB but
// time unchanged -> writes proven NOT the cost). Reverting to the fastest
// measured variant. Kernel LDS now 5 KB (vs r2's 33) -> better occupancy.
// ---------------------------------------------------------------------------
__global__ __launch_bounds__(256) void proj_bin_kernel(
    const float* __restrict__ X, const unsigned short* __restrict__ wfrag,
    float* __restrict__ Q, unsigned int* __restrict__ KVp,
    const int* __restrict__ er, const int* __restrict__ ec,
    int* __restrict__ fill, unsigned int* __restrict__ pairs)
{
    __shared__ int lcnt[NB];   // 5 KB

    const int t = threadIdx.x;
    const int mod = blockIdx.x % 3;

    if (mod != 2) {
        // ---------------- projection (LDS-free, r2/r5-verified) ----------------
        const int pb = (blockIdx.x / 3) * 2 + mod;
        if (pb >= PROJ_B) return;
        const int lane = t & 63;
        const int w    = t >> 6;
        const int quad = lane >> 4;
        const int m16  = lane & 15;
        const int row0 = pb * MTILE;

        const int arow = w * 16 + m16;
        const int grc  = min(row0 + arow, N_NODES - 1);   // clamp; never stored
        const float* xrow = X + (size_t)grc * D_IN;

        floatx4 acc[6];
#pragma unroll
        for (int nt = 0; nt < 6; nt++) acc[nt] = (floatx4)0.f;

#pragma unroll
        for (int s = 0; s < 8; s++) {
            const float4 a0 = *(const float4*)(xrow + s * 32 + quad * 8);
            const float4 a1 = *(const float4*)(xrow + s * 32 + quad * 8 + 4);
            union { bf16x8 v; unsigned short u[8]; } af;
            af.u[0] = f2bf(a0.x); af.u[1] = f2bf(a0.y);
            af.u[2] = f2bf(a0.z); af.u[3] = f2bf(a0.w);
            af.u[4] = f2bf(a1.x); af.u[5] = f2bf(a1.y);
            af.u[6] = f2bf(a1.z); af.u[7] = f2bf(a1.w);
            bf16x8 bfr[6];
#pragma unroll
            for (int nt = 0; nt < 6; nt++)
                bfr[nt] = *(const bf16x8*)(wfrag + (((s * 6 + nt) * 64 + lane) * 8));
#pragma unroll
            for (int nt = 0; nt < 6; nt++)
                acc[nt] = __builtin_amdgcn_mfma_f32_16x16x32_bf16(af.v, bfr[nt], acc[nt], 0, 0, 0);
        }

#pragma unroll
        for (int i = 0; i < 4; i++) {
            const int gr = row0 + w * 16 + quad * 4 + i;
            if (gr < N_NODES) {
#pragma unroll
                for (int nt = 0; nt < 2; nt++)
                    Q[gr * HS + nt * 16 + m16] = acc[nt][i];
#pragma unroll
                for (int p = 0; p < 2; p++) {
                    const int j = p * 16 + m16;
                    const unsigned kb = f2bf(acc[2 + p][i]);
                    const unsigned vb = f2bf(acc[4 + p][i]);
                    KVp[gr * HS + j] = (kb << 16) | vb;
                }
            }
        }
    } else {
        // ---------------- edge binning (r2-exact: direct scatter) ----------------
        const int bb = blockIdx.x / 3;
        const int e0 = bb * EPB;
        const int e1 = min(e0 + EPB, N_EDGES);

        for (int b = t; b < NB; b += 256) lcnt[b] = 0;
        __syncthreads();

        int rl[16], cl[16];
#pragma unroll
        for (int i = 0; i < 16; i++) {
            const int e = e0 + t + i * 256;
            if (e < e1) {
                rl[i] = er[e];
                cl[i] = ec[e];
                atomicAdd(&lcnt[rl[i] / ROWS_PB], 1);
            }
        }
        __syncthreads();

        for (int b = t; b < NB; b += 256) {
            const int c = lcnt[b];
            lcnt[b] = (c > 0) ? atomicAdd(&fill[b], c) : 0;  // base slot
        }
        __syncthreads();

#pragma unroll
        for (int i = 0; i < 16; i++) {
            const int e = e0 + t + i * 256;
            if (e < e1) {
                const int r = rl[i];
                const int b = r / ROWS_PB;
                const int slot = atomicAdd(&lcnt[b], 1);
                pairs[(size_t)b * CAP + slot] =
                    ((unsigned)(r - b * ROWS_PB) << 16) | (unsigned)cl[i];
            }
        }
    }
}

// ---------------------------------------------------------------------------
// r6 NEW: fused place + aggregate. One block per bucket (1250 blocks).
// Loads the bucket's pairs into registers, per-wave-privatized LDS row
// histogram + 40-wide scan + scatter of cols into LDS `srt` (= place's sort,
// minus ALL its global outputs: no rowptr, no col_sorted, no cross-bucket
// base reduction), then aggregates the bucket's 40 rows in-block (10 per
// wave) with the 8-slot x 8-comp wave layout, cols read from LDS.
// Removes one dispatch + 13 MB global round-trip. ~7.5 KB LDS -> 5000 waves
// resident for gather latency hiding.
// ---------------------------------------------------------------------------
__global__ __launch_bounds__(256) void bucket_agg_kernel(
    const unsigned int* __restrict__ pairs, const int* __restrict__ fill,
    const float* __restrict__ Q, const unsigned int* __restrict__ KVp,
    float* __restrict__ out)
{
    __shared__ unsigned srt[CAP];          // cols sorted by local row (6.4 KB)
    __shared__ int hist[4][ROWS_PB];       // per-wave histograms -> scatter bases
    __shared__ int sc[64];                 // scan buffer
    __shared__ int rowstart[ROWS_PB + 1];

    const int b = blockIdx.x;
    const int t = threadIdx.x;
    const int w = t >> 6;
    const int n = fill[b];
    const unsigned int* pbk = pairs + (size_t)b * CAP;

    for (int i = t; i < 4 * ROWS_PB; i += 256) ((int*)hist)[i] = 0;
    __syncthreads();

    unsigned pl[(CAP + 255) / 256];
#pragma unroll
    for (int k = 0; k < (CAP + 255) / 256; k++) {
        const int i = t + k * 256;
        if (i < n) {
            pl[k] = pbk[i];
            atomicAdd(&hist[w][pl[k] >> 16], 1);   // own wave's copy
        }
    }
    __syncthreads();

    // 40-wide inclusive scan of per-row totals
    if (t < 64)
        sc[t] = (t < ROWS_PB) ? (hist[0][t] + hist[1][t] + hist[2][t] + hist[3][t]) : 0;
    __syncthreads();
#pragma unroll
    for (int ofs = 1; ofs < 64; ofs <<= 1) {
        int u = 0;
        if (t < 64 && t >= ofs) u = sc[t - ofs];
        __syncthreads();
        if (t < 64) sc[t] += u;
        __syncthreads();
    }
    if (t < ROWS_PB) {
        const int h0 = hist[0][t], h1 = hist[1][t], h2 = hist[2][t], h3 = hist[3][t];
        const int excl = sc[t] - (h0 + h1 + h2 + h3);
        rowstart[t] = excl;
        int run = excl;
        hist[0][t] = run; run += h0;
        hist[1][t] = run; run += h1;
        hist[2][t] = run; run += h2;
        hist[3][t] = run;
    }
    if (t == 0) rowstart[ROWS_PB] = n;
    __syncthreads();

#pragma unroll
    for (int k = 0; k < (CAP + 255) / 256; k++) {
        const int i = t + k * 256;
        if (i < n) {
            const unsigned p = pl[k];
            const int pos = atomicAdd(&hist[w][p >> 16], 1);  // own wave's counter
            srt[pos] = p & 0xFFFFu;
        }
    }
    __syncthreads();

    // ---- aggregation: wave w handles rows w, w+4, ..., w+36 ----
    const int lane = t & 63;
    const int comp = lane & 7;
    const int slot = lane >> 3;
    const float scale = 0.17677669529663687f;  // 1/sqrt(32)

#pragma unroll
    for (int rr = 0; rr < ROWS_PB / 4; rr++) {
        const int lr = w + rr * 4;
        const int gr = b * ROWS_PB + lr;
        const float4 q4 = *(const float4*)(Q + gr * HS + comp * 4);
        const int start = rowstart[lr];
        const int end   = rowstart[lr + 1];
        const int last  = end - 1;

        float accD = 0.f;
        float n0 = 0.f, n1 = 0.f, n2 = 0.f, n3 = 0.f;

        for (int e0 = start; e0 < end; e0 += 32) {
            int   cc[4];
            uint4 kv[4];
#pragma unroll
            for (int bb = 0; bb < 4; bb++)
                if (e0 + 8 * bb < end)
                    cc[bb] = (int)srt[min(e0 + 8 * bb + slot, last)];
#pragma unroll
            for (int bb = 0; bb < 4; bb++)
                if (e0 + 8 * bb < end)
                    kv[bb] = *(const uint4*)(KVp + (size_t)cc[bb] * HS + comp * 4);
#pragma unroll
            for (int bb = 0; bb < 4; bb++) {
                if (e0 + 8 * bb < end) {
                    float p = q4.x * __uint_as_float(kv[bb].x & 0xFFFF0000u)
                            + q4.y * __uint_as_float(kv[bb].y & 0xFFFF0000u)
                            + q4.z * __uint_as_float(kv[bb].z & 0xFFFF0000u)
                            + q4.w * __uint_as_float(kv[bb].w & 0xFFFF0000u);
#pragma unroll
                    for (int ofs = 1; ofs < 8; ofs <<= 1)
                        p += __shfl_xor(p, ofs, 64);
                    const float ex = (e0 + 8 * bb + slot < end) ? __expf(p * scale) : 0.f;
                    accD += ex;
                    n0 += ex * __uint_as_float(kv[bb].x << 16);
                    n1 += ex * __uint_as_float(kv[bb].y << 16);
                    n2 += ex * __uint_as_float(kv[bb].z << 16);
                    n3 += ex * __uint_as_float(kv[bb].w << 16);
                }
            }
        }

        // reduce over the 8 slots
#pragma unroll
        for (int ofs = 8; ofs < 64; ofs <<= 1) {
            accD += __shfl_xor(accD, ofs, 64);
            n0 += __shfl_xor(n0, ofs, 64);
            n1 += __shfl_xor(n1, ofs, 64);
            n2 += __shfl_xor(n2, ofs, 64);
            n3 += __shfl_xor(n3, ofs, 64);
        }

        if (slot == 0) {
            const float inv = (accD > 0.f) ? 1.f / accD : 0.f;
            float4 o;
            o.x = n0 * inv; o.y = n1 * inv; o.z = n2 * inv; o.w = n3 * inv;
            *(float4*)(out + gr * HS + comp * 4) = o;
        }
    }
}

extern "C" void kernel_launch(void* const* d_in, const int* in_sizes, int n_in,
                              void* d_out, int out_size, void* d_ws, size_t ws_size,
                              hipStream_t stream)
{
    const float* X  = (const float*)d_in[0];
    const float* Wq = (const float*)d_in[1];
    const float* Wk = (const float*)d_in[2];
    const float* Wv = (const float*)d_in[3];
    const int*   ei = (const int*)d_in[4];
    const int* er = ei;
    const int* ec = ei + N_EDGES;

    float* out = (float*)d_out;

    // workspace: Q | KVp | fill | wfrag | pairs
    float* Q          = (float*)d_ws;
    unsigned int* KVp = (unsigned int*)(Q + (size_t)N_NODES * HS);
    int* fill         = (int*)(KVp + (size_t)N_NODES * HS);
    unsigned short* wfrag = (unsigned short*)(fill + NB);
    unsigned int* pairs   = (unsigned int*)(wfrag + 8 * 6 * 64 * 8);

    hipMemsetAsync(fill, 0, NB * sizeof(int), stream);

    wfrag_kernel<<<(8 * 6 * 64 * 8 + 255) / 256, 256, 0, stream>>>(
        Wq, Wk, Wv, wfrag);

    proj_bin_kernel<<<GRID_F, 256, 0, stream>>>(
        X, wfrag, Q, KVp, er, ec, fill, pairs);

    bucket_agg_kernel<<<NB, 256, 0, stream>>>(pairs, fill, Q, KVp, out);
}